// Round 8
// baseline (180.455 us; speedup 1.0000x reference)
//
#include <hip/hip_runtime.h>
#include <hip/hip_bf16.h>

// GAT layer, N=8192 Fin=256 Fout=64.
// k1: Wh = h@W, s1/s2 = Wh@a halves (s2 pre-scaled by log2e), whT hi/lo bf16.
// k2 v7: barrier-free fused attention, pipelined via global_load_lds DMA:
//   - per-wave private 3-slot LDS pipe (4KB/slot: adj 2KB + whT hi/lo 2KB).
//     DMA has no dest VGPRs -> regalloc cannot clobber (R6/R7 crash mechanism),
//     scheduler cannot sink (side-effecting). Counted s_waitcnt vmcnt(8),
//     never 0 in loop; lgkmcnt(0) before re-staging a consumed slot.
//   - per-lane global source addrs, linear LDS dest, stride-16B readback
//     (conflict-free b128 pattern).
//   - P computed per-thread directly in mfma_f32_32x32x16_bf16 B-frag layout;
//     fixed row-max bound m=lrelu(s1+16); 3-MFMA bf16 hi/lo split.

typedef __attribute__((ext_vector_type(8))) short bf16x8;
typedef __attribute__((ext_vector_type(16))) float f32x16;

#define QB 32
#define KS 16
#define NS 128   // ksteps per wave = 2048/16
#define LOG2E 1.4426950408889634f

__device__ __forceinline__ uint pk2(float a, float b, float& ra, float& rb) {
    __hip_bfloat162 h = __float22bfloat162_rn(make_float2(a, b));
    float2 f = __bfloat1622float2(h);
    ra = f.x; rb = f.y;
    union { __hip_bfloat162 b; uint u; } c; c.b = h; return c.u;
}
__device__ __forceinline__ uint pk2o(float a, float b) {
    __hip_bfloat162 h = __float22bfloat162_rn(make_float2(a, b));
    union { __hip_bfloat162 b; uint u; } c; c.b = h; return c.u;
}
__device__ __forceinline__ ushort f2bf(float x) {
    union { __hip_bfloat16 b; ushort u; } c;
    c.b = __float2bfloat16(x);
    return c.u;
}
__device__ __forceinline__ float bf2f(ushort u) {
    union { ushort u; __hip_bfloat16 b; } c;
    c.u = u;
    return __bfloat162float(c.b);
}

// 16B global->LDS DMA. gptr is PER-LANE; LDS dest = uniform base + lane*16.
__device__ __forceinline__ void gload_lds16(const void* g, void* l) {
    __builtin_amdgcn_global_load_lds(
        (const __attribute__((address_space(1))) unsigned int*)g,
        (__attribute__((address_space(3))) unsigned int*)l,
        16, 0, 0);
}

// ---------------- kernel 1: Wh, s1, s2*log2e, WhT hi/lo ----------------
__global__ __launch_bounds__(256) void k1_wh(
    const float* __restrict__ h, const float* __restrict__ W,
    const float* __restrict__ a,
    float* __restrict__ s1, float* __restrict__ s2,
    ushort* __restrict__ whT_hi, ushort* __restrict__ whT_lo)
{
    const int l = threadIdx.x & 63;      // lane = output feature
    const int w = threadIdx.x >> 6;
    const int row0 = blockIdx.x * 16 + w * 4;

    float acc[4] = {0.f, 0.f, 0.f, 0.f};
    for (int k = 0; k < 256; k += 4) {
        float w0 = W[(k + 0) * 64 + l];
        float w1 = W[(k + 1) * 64 + l];
        float w2 = W[(k + 2) * 64 + l];
        float w3 = W[(k + 3) * 64 + l];
#pragma unroll
        for (int r = 0; r < 4; ++r) {
            const float4 hv = *reinterpret_cast<const float4*>(&h[(row0 + r) * 256 + k]);
            acc[r] = fmaf(hv.x, w0, acc[r]);
            acc[r] = fmaf(hv.y, w1, acc[r]);
            acc[r] = fmaf(hv.z, w2, acc[r]);
            acc[r] = fmaf(hv.w, w3, acc[r]);
        }
    }
    const float a1 = a[l];
    const float a2 = a[64 + l];
#pragma unroll
    for (int r = 0; r < 4; ++r) {
        const int row = row0 + r;
        float x1 = acc[r] * a1;
        float x2 = acc[r] * a2;
#pragma unroll
        for (int m = 32; m >= 1; m >>= 1) {
            x1 += __shfl_xor(x1, m);
            x2 += __shfl_xor(x2, m);
        }
        if (l == 0) { s1[row] = x1; s2[row] = x2 * LOG2E; }
        const ushort hi = f2bf(acc[r]);
        const ushort lo = f2bf(acc[r] - bf2f(hi));
        whT_hi[l * 8192 + row] = hi;
        whT_lo[l * 8192 + row] = lo;
    }
}

// ---------------- kernel 2: DMA-pipelined fused attention ----------------

// stage kstep T_ into slot SL (4 DMA ops = 4 vmcnt units)
#define STAGE(SL, T_) do { \
    unsigned char* sb_ = wbase + (SL) * 4096; \
    const size_t jq_ = (size_t)(T_) * KS; \
    gload_lds16(aptrA + jq_,     sb_); \
    gload_lds16(aptrA + jq_ + 8, sb_ + 1024); \
    gload_lds16(whp + jq_,       sb_ + 2048); \
    gload_lds16(wlp + jq_,       sb_ + 3072); \
  } while (0)

// t1,t2 in log2 domain (s2 pre-scaled by log2e in k1)
#define PEXP(dst, a_, s_) { \
    const float t1_ = A + (s_); \
    const float t2_ = fmaf(0.2f, (s_), A5); \
    dst = __builtin_amdgcn_exp2f(fmaxf(t1_, t2_)); \
    if ((a_) <= 0) dst = 0.0f; \
    rs += dst; }

// one kstep: counted wait, slot readback, (re)stage, P-compute, 3 MFMA
#define DO_STEP(SL, T_, WN, DO_STG) do { \
    asm volatile("s_waitcnt vmcnt(" #WN ")" ::: "memory"); \
    __builtin_amdgcn_sched_barrier(0); \
    const unsigned char* pb_ = wbase + (SL) * 4096; \
    const int4   aA = *(const int4*)(pb_ + adjoff); \
    const int4   aB = *(const int4*)(pb_ + adjoff + 512); \
    const bf16x8 whh = *(const bf16x8*)(pb_ + whoff); \
    const bf16x8 whl = *(const bf16x8*)(pb_ + whoff + 1024); \
    const int j0l_ = (T_) * KS + kh * 8; \
    const float4 s20 = *(const float4*)&s2l[ks][j0l_]; \
    const float4 s21 = *(const float4*)&s2l[ks][j0l_ + 4]; \
    asm volatile("s_waitcnt lgkmcnt(0)" ::: "memory"); \
    __builtin_amdgcn_sched_barrier(0); \
    if (DO_STG) STAGE(SL, (T_) + 3); \
    float p0,p1,p2,p3,p4,p5,p6,p7, r0,r1,r2,r3,r4,r5,r6,r7; \
    PEXP(p0, aA.x, s20.x) \
    PEXP(p1, aA.y, s20.y) \
    PEXP(p2, aA.z, s20.z) \
    PEXP(p3, aA.w, s20.w) \
    PEXP(p4, aB.x, s21.x) \
    PEXP(p5, aB.y, s21.y) \
    PEXP(p6, aB.z, s21.z) \
    PEXP(p7, aB.w, s21.w) \
    union PKU { bf16x8 v; uint u[4]; } bh_, bl_; \
    bh_.u[0] = pk2(p0, p1, r0, r1); \
    bh_.u[1] = pk2(p2, p3, r2, r3); \
    bh_.u[2] = pk2(p4, p5, r4, r5); \
    bh_.u[3] = pk2(p6, p7, r6, r7); \
    bl_.u[0] = pk2o(p0 - r0, p1 - r1); \
    bl_.u[1] = pk2o(p2 - r2, p3 - r3); \
    bl_.u[2] = pk2o(p4 - r4, p5 - r5); \
    bl_.u[3] = pk2o(p6 - r6, p7 - r7); \
    acc = __builtin_amdgcn_mfma_f32_32x32x16_bf16(whh, bh_.v, acc, 0, 0, 0); \
    acc = __builtin_amdgcn_mfma_f32_32x32x16_bf16(whh, bl_.v, acc, 0, 0, 0); \
    acc = __builtin_amdgcn_mfma_f32_32x32x16_bf16(whl, bh_.v, acc, 0, 0, 0); \
  } while (0)

__global__ __launch_bounds__(512, 2) void k2_attn(
    const int* __restrict__ adj,
    const float* __restrict__ s1g, const float* __restrict__ s2g,
    const ushort* __restrict__ whT_hi, const ushort* __restrict__ whT_lo,
    float* __restrict__ out)
{
    __shared__ __align__(16) unsigned char pipe[8 * 3 * 4096];  // 96KB: [wave][slot][adjA|adjB|whH|whL]
    __shared__ __align__(16) float s2l[4][2048];                // 32KB: per-quarter s2 slice
    __shared__ __align__(16) float slds[2][3][64][16];          // 24KB: ks 1..3 partial accs
    __shared__ float dlds[4][32];                               // per-quarter denoms

    const int t   = threadIdx.x;
    const int l   = t & 63;
    const int wv  = t >> 6;
    const int ft  = wv >> 2;          // 0..1 : feature half (32 feats)
    const int ks  = wv & 3;           // 0..3 : j quarter (2048 cols)
    const int row = l & 31;           // node-row within tile = B-frag col
    const int kh  = l >> 5;           // k-half within fragment
    const int i0  = blockIdx.x * QB;
    const int ftbase = ft * 32;
    const int jbase  = ks * 2048;

    unsigned char* wbase = &pipe[wv * 12288];

    const float s1v = s1g[i0 + row];
    const float mq  = s1v + 16.0f;
    const float m   = fmaxf(mq, 0.2f * mq);       // fixed row-max upper bound
    const float A   = (s1v - m) * LOG2E;          // log2-domain constants
    const float A5  = fmaf(0.2f, s1v, -m) * LOG2E;

    // per-lane global source pointers
    const int*    aptrA = adj    + (size_t)(i0 + row) * 8192 + jbase + kh * 4;
    const ushort* whp   = whT_hi + (size_t)(ftbase + row) * 8192 + jbase + kh * 8;
    const ushort* wlp   = whT_lo + (size_t)(ftbase + row) * 8192 + jbase + kh * 8;

    // readback offsets (stride-16B linear -> conflict-free)
    const int adjoff = kh * 1024 + row * 16;
    const int whoff  = 2048 + l * 16;

    // prologue: stage s2 quarter (ft0 waves) + pipe slots 0..2, then drain
    if (ft == 0) {
#pragma unroll
        for (int q = 0; q < 8; ++q)
            gload_lds16(s2g + jbase + q * 256 + l * 4, &s2l[ks][q * 256]);
    }
    STAGE(0, 0); STAGE(1, 1); STAGE(2, 2);
    __syncthreads();    // drains vmcnt: s2l + slots 0..2 ready; in-loop counts exact

    f32x16 acc = {0.f,0.f,0.f,0.f,0.f,0.f,0.f,0.f,0.f,0.f,0.f,0.f,0.f,0.f,0.f,0.f};
    float rs = 0.f;

    int slot = 0;
    for (int T = 0; T < NS - 3; ++T) {            // T = 0..124
        DO_STEP(slot, T, 8, true);                // (T+3)%3 == T%3: restage same slot
        slot = (slot == 2) ? 0 : slot + 1;
    }
    DO_STEP(2, 125, 8, false);                    // drain tail
    DO_STEP(0, 126, 4, false);
    DO_STEP(1, 127, 0, false);

    // ---- epilogue: combine 4 ks-partials ----
    rs += __shfl_xor(rs, 32);               // lanes l, l+32 hold same row
    if (ft == 0 && kh == 0) dlds[ks][row] = rs;
    if (ks != 0) {
        float4* dst = reinterpret_cast<float4*>(&slds[ft][ks - 1][l][0]);
        dst[0] = make_float4(acc[0],  acc[1],  acc[2],  acc[3]);
        dst[1] = make_float4(acc[4],  acc[5],  acc[6],  acc[7]);
        dst[2] = make_float4(acc[8],  acc[9],  acc[10], acc[11]);
        dst[3] = make_float4(acc[12], acc[13], acc[14], acc[15]);
    }
    __syncthreads();
    if (ks == 0) {
#pragma unroll
        for (int s = 0; s < 3; ++s) {
            const float4* src = reinterpret_cast<const float4*>(&slds[ft][s][l][0]);
            const float4 v0 = src[0], v1 = src[1], v2 = src[2], v3 = src[3];
            acc[0]  += v0.x; acc[1]  += v0.y; acc[2]  += v0.z; acc[3]  += v0.w;
            acc[4]  += v1.x; acc[5]  += v1.y; acc[6]  += v1.z; acc[7]  += v1.w;
            acc[8]  += v2.x; acc[9]  += v2.y; acc[10] += v2.z; acc[11] += v2.w;
            acc[12] += v3.x; acc[13] += v3.y; acc[14] += v3.z; acc[15] += v3.w;
        }
        const float den = dlds[0][row] + dlds[1][row] + dlds[2][row] + dlds[3][row];
        const float inv = 1.0f / den;
        const int orow = i0 + row;
        // D layout (32x32): col=l&31 -> node row; feat = (reg&3)+8*(reg>>2)+4*kh
#pragma unroll
        for (int g = 0; g < 4; ++g) {
            float4 o; float x;
            x = acc[g * 4 + 0] * inv; o.x = (x > 0.f) ? x : expm1f(x);
            x = acc[g * 4 + 1] * inv; o.y = (x > 0.f) ? x : expm1f(x);
            x = acc[g * 4 + 2] * inv; o.z = (x > 0.f) ? x : expm1f(x);
            x = acc[g * 4 + 3] * inv; o.w = (x > 0.f) ? x : expm1f(x);
            *reinterpret_cast<float4*>(&out[orow * 64 + ftbase + 8 * g + 4 * kh]) = o;
        }
    }
}

extern "C" void kernel_launch(void* const* d_in, const int* in_sizes, int n_in,
                              void* d_out, int out_size, void* d_ws, size_t ws_size,
                              hipStream_t stream) {
    const float* h   = (const float*)d_in[0];
    const int*   adj = (const int*)d_in[1];
    const float* W   = (const float*)d_in[2];
    const float* a   = (const float*)d_in[3];
    float* out = (float*)d_out;

    float*  s1     = (float*)d_ws;                 // 8192 f32
    float*  s2     = s1 + 8192;                    // 8192 f32 (pre-scaled log2e)
    ushort* whT_hi = (ushort*)(s2 + 8192);         // [64][8192] bf16
    ushort* whT_lo = whT_hi + 64 * 8192;           // [64][8192] bf16

    hipLaunchKernelGGL(k1_wh, dim3(512), dim3(256), 0, stream,
                       h, W, a, s1, s2, whT_hi, whT_lo);
    hipLaunchKernelGGL(k2_attn, dim3(256), dim3(512), 0, stream,
                       adj, s1, s2, whT_hi, whT_lo, out);
}